// Round 6
// baseline (1282.781 us; speedup 1.0000x reference)
//
#include <hip/hip_runtime.h>
#include <hip/hip_bf16.h>

// QLSTM: T=512, B=256, D=128, H=256, P=128, GAMMA=1
// Phase 1 (MFMA GEMM): sx[r,p] = ||x_r||^2 + ||px_p||^2 - 2 x_r.px_p  (full Sx, f16, 32MB ws)
// Phase 2: 256 WGs (1 batch row each) x 1024 threads (16 waves, 4/SIMD).
//   Round-6 restructure: round-4/5 kept 160 regs of MFMA fragments under a 124-reg
//   arch budget -> AGPR parking + ~200 v_accvgpr copies/wave/step (the phantom VALU
//   load), at only 2 waves/SIMD. Now: wave w owns h=[w*16,w*16+16) x all 4 gates
//   (wfrag = 16 h8 = 64 regs, pinned); -2*proto_h lives in LDS (padded rows, 2-way
//   bank aliasing = free) so Sh B-frags are transient ds_reads. Total demand ~120
//   regs <= 128 cap at 4 waves/SIMD: no AGPR traffic, 2x latency hiding.
//   Waves 0-7 do Sh (8 MFMA, fused |hx|^2 fdot2, exp, klds); all 16 do gates
//   (16 MFMA); in-register cell update; 2 lgkm-only barriers/step.

#define TT 512
#define BB 256
#define DD 128
#define HH 256
#define PP 128
#define DHH 384

typedef _Float16 h2 __attribute__((ext_vector_type(2)));
typedef _Float16 h8 __attribute__((ext_vector_type(8)));
typedef float f4v __attribute__((ext_vector_type(4)));

union H8 { h8 v; h2 h[4]; };

__device__ __forceinline__ void pin_h8(h8& v) { asm volatile("" : "+v"(v)); }

// barrier with LDS-only drain: global loads/stores stay in flight.
__device__ __forceinline__ void bar_lds() {
  asm volatile("s_waitcnt lgkmcnt(0)" ::: "memory");
  __builtin_amdgcn_s_barrier();
}

__device__ __forceinline__ float fdot2f(h2 a, h2 b, float c) {
#if __has_builtin(__builtin_amdgcn_fdot2)
  return __builtin_amdgcn_fdot2(a, b, c, false);
#else
  return c + (float)a.x * (float)b.x + (float)a.y * (float)b.y;
#endif
}

__device__ __forceinline__ float sigm_f(float x) { return 1.f / (1.f + __expf(-x)); }
__device__ __forceinline__ float tanh_f(float x) { return 1.f - 2.f / (1.f + __expf(2.f * x)); }

__device__ __forceinline__ h8 pack_h8(float4 a, float4 b2, float s) {
  h8 v;
  v[0] = (_Float16)(s * a.x);  v[1] = (_Float16)(s * a.y);
  v[2] = (_Float16)(s * a.z);  v[3] = (_Float16)(s * a.w);
  v[4] = (_Float16)(s * b2.x); v[5] = (_Float16)(s * b2.y);
  v[6] = (_Float16)(s * b2.z); v[7] = (_Float16)(s * b2.w);
  return v;
}

// ---------------- Phase 1: Sx via MFMA f16 ----------------
__global__ __launch_bounds__(256, 2) void sx_kernel(const float* __restrict__ x,
                                                    const float* __restrict__ proto,
                                                    _Float16* __restrict__ sx) {
  __shared__ __align__(16) _Float16 qlds[PP * 136];   // -2*proto_x, f16
  __shared__ __align__(16) _Float16 xlds[64 * 136];   // x tile, f16
  __shared__ float pnlds[PP];
  __shared__ float xnlds[64];

  const int t = threadIdx.x;
  const int lane = t & 63;
  const int wv = t >> 6;          // wave 0..3 -> m-tile
  const int col = lane & 15;
  const int quad = lane >> 4;
  const int r0 = blockIdx.x * 256;

  // ---- stage q = -2*proto_x (f16) + pnorm ----
  {
    const int p = t >> 1;
    const int hh = t & 1;
    const float* src = proto + p * DHH + hh * 64;
    _Float16* dst = qlds + p * 136 + hh * 64;
    float pn = 0.f;
#pragma unroll
    for (int i = 0; i < 8; ++i) {
      float4 a = *(const float4*)(src + i * 8);
      float4 b = *(const float4*)(src + i * 8 + 4);
      pn = fmaf(a.x, a.x, fmaf(a.y, a.y, fmaf(a.z, a.z, fmaf(a.w, a.w, pn))));
      pn = fmaf(b.x, b.x, fmaf(b.y, b.y, fmaf(b.z, b.z, fmaf(b.w, b.w, pn))));
      *(h8*)(dst + i * 8) = pack_h8(a, b, -2.f);
    }
    pn += __shfl_xor(pn, 1);
    if (hh == 0) pnlds[p] = pn;
  }

  // ---- stage x tile 0 ----
  {
    const int m = t >> 2;
    const int q4 = t & 3;
    const float* xs = x + ((size_t)(r0 + m)) * DD + q4 * 32;
    _Float16* xd = xlds + m * 136 + q4 * 32;
    float xn = 0.f;
#pragma unroll
    for (int i = 0; i < 4; ++i) {
      float4 a = *(const float4*)(xs + i * 8);
      float4 b = *(const float4*)(xs + i * 8 + 4);
      xn = fmaf(a.x, a.x, fmaf(a.y, a.y, fmaf(a.z, a.z, fmaf(a.w, a.w, xn))));
      xn = fmaf(b.x, b.x, fmaf(b.y, b.y, fmaf(b.z, b.z, fmaf(b.w, b.w, xn))));
      *(h8*)(xd + i * 8) = pack_h8(a, b, 1.f);
    }
    xn += __shfl_xor(xn, 1);
    xn += __shfl_xor(xn, 2);
    if (q4 == 0) xnlds[m] = xn;
  }
  __syncthreads();

  float pn8[8];
#pragma unroll
  for (int nt = 0; nt < 8; ++nt) pn8[nt] = pnlds[nt * 16 + col];

  for (int tile = 0; tile < 4; ++tile) {
    h8 af[4];
#pragma unroll
    for (int kc = 0; kc < 4; ++kc)
      af[kc] = *(const h8*)(xlds + (wv * 16 + col) * 136 + kc * 32 + quad * 8);
    float xnq[4];
#pragma unroll
    for (int r = 0; r < 4; ++r) xnq[r] = xnlds[wv * 16 + quad * 4 + r];

#pragma unroll
    for (int nt = 0; nt < 8; ++nt) {
      f4v acc;
      acc[0] = pn8[nt]; acc[1] = pn8[nt]; acc[2] = pn8[nt]; acc[3] = pn8[nt];
#pragma unroll
      for (int kc = 0; kc < 4; ++kc) {
        h8 bf = *(const h8*)(qlds + (nt * 16 + col) * 136 + kc * 32 + quad * 8);
        acc = __builtin_amdgcn_mfma_f32_16x16x32_f16(af[kc], bf, acc, 0, 0, 0);
      }
#pragma unroll
      for (int r = 0; r < 4; ++r) {
        const int row = r0 + tile * 64 + wv * 16 + quad * 4 + r;
        sx[(size_t)row * PP + nt * 16 + col] = (_Float16)(acc[r] + xnq[r]);
      }
    }

    if (tile < 3) {
      __syncthreads();
      const int m = t >> 2;
      const int q4 = t & 3;
      const float* xs = x + ((size_t)(r0 + (tile + 1) * 64 + m)) * DD + q4 * 32;
      _Float16* xd = xlds + m * 136 + q4 * 32;
      float xn = 0.f;
#pragma unroll
      for (int i = 0; i < 4; ++i) {
        float4 a = *(const float4*)(xs + i * 8);
        float4 b = *(const float4*)(xs + i * 8 + 4);
        xn = fmaf(a.x, a.x, fmaf(a.y, a.y, fmaf(a.z, a.z, fmaf(a.w, a.w, xn))));
        xn = fmaf(b.x, b.x, fmaf(b.y, b.y, fmaf(b.z, b.z, fmaf(b.w, b.w, xn))));
        *(h8*)(xd + i * 8) = pack_h8(a, b, 1.f);
      }
      xn += __shfl_xor(xn, 1);
      xn += __shfl_xor(xn, 2);
      if (q4 == 0) xnlds[m] = xn;
      __syncthreads();
    }
  }
}

// ---------------- Phase 2: sequential recurrence (MFMA GEMV, 16 waves) ----------------
__global__ __launch_bounds__(1024, 4) void rec_kernel(
    const _Float16* __restrict__ sx, const float* __restrict__ proto,
    const float* __restrict__ Wf, const float* __restrict__ bfv,
    const float* __restrict__ Wi, const float* __restrict__ biv,
    const float* __restrict__ Wg, const float* __restrict__ bgv,
    const float* __restrict__ Wo, const float* __restrict__ bov,
    float* __restrict__ out) {
  const int b = blockIdx.x;
  const int t = threadIdx.x;
  const int w = t >> 6;     // wave 0..15
  const int l = t & 63;
  const int lc = l & 15;    // B-frag column / C column
  const int lg = l >> 4;    // k-group 0..3 (8 contiguous k elems each)

  // -2*proto_h in LDS: 128 rows x 264 halves (pad: 528B stride -> 2-way banks, free)
  __shared__ __align__(16) _Float16 plds[PP * 264];
  __shared__ float pnlds[PP];
  __shared__ __align__(16) _Float16 hxlds[HH];
  __shared__ __align__(16) _Float16 klds[PP];

  // ---- stage -2*proto_h + pnorm: thread covers (p = t>>3, 32 halves at (t&7)*32)
  {
    const int sp = t >> 3;
    const int scc = t & 7;
    const float* src = proto + (size_t)sp * DHH + DD + scc * 32;
    _Float16* dst = plds + sp * 264 + scc * 32;
    float pnp = 0.f;
#pragma unroll
    for (int i = 0; i < 4; ++i) {
      float4 a = *(const float4*)(src + i * 8);
      float4 c = *(const float4*)(src + i * 8 + 4);
      pnp = fmaf(a.x, a.x, fmaf(a.y, a.y, fmaf(a.z, a.z, fmaf(a.w, a.w, pnp))));
      pnp = fmaf(c.x, c.x, fmaf(c.y, c.y, fmaf(c.z, c.z, fmaf(c.w, c.w, pnp))));
      *(h8*)(dst + i * 8) = pack_h8(a, c, -2.f);
    }
    pnp += __shfl_xor(pnp, 1);
    pnp += __shfl_xor(pnp, 2);
    pnp += __shfl_xor(pnp, 4);
    if (scc == 0) pnlds[sp] = pnp;
  }
  if (t < HH) hxlds[t] = (_Float16)0.f;

  // ---- gate weights: wave w owns h = w*16 + lc, all 4 gates (16 h8 = 64 VGPRs)
  const int h = w * 16 + lc;
  const float* const Warr[4] = {Wf, Wi, Wg, Wo};
  const float* const barr[4] = {bfv, biv, bgv, bov};
  h8 wfrag[4][4];
  float bias[4];
#pragma unroll
  for (int g = 0; g < 4; ++g) {
    const float* row = Warr[g] + (size_t)h * PP;
    bias[g] = barr[g][h];
#pragma unroll
    for (int c = 0; c < 4; ++c) {
      float4 a = *(const float4*)(row + c * 32 + lg * 8);
      float4 b2 = *(const float4*)(row + c * 32 + lg * 8 + 4);
      wfrag[g][c] = pack_h8(a, b2, 1.f);
    }
  }
#pragma unroll
  for (int g = 0; g < 4; ++g)
#pragma unroll
    for (int c = 0; c < 4; ++c) pin_h8(wfrag[g][c]);

  __syncthreads();  // plds/pnlds/hxlds ready

  const int p = (w & 7) * 16 + lc;   // Sh prototype (valid dup for all waves)
  const float pn = pnlds[p];
  float sx_next = 0.f;
  if (w < 8) sx_next = (float)sx[(size_t)b * PP + p];

  float cx = 0.f, hx = 0.f;
  const f4v zacc = {0.f, 0.f, 0.f, 0.f};

  for (int step = 0; step < TT; ++step) {
    // ---- Sh (waves 0-7): d2 = |hx|^2 - 2 hx.ph + |ph|^2 + sx ; k = exp(-d2) ----
    if (w < 8) {
      const float sx_cur = sx_next;
      const int nst = (step + 1 < TT) ? (step + 1) : (TT - 1);
      sx_next = (float)sx[((size_t)nst * BB + b) * PP + p];

      f4v accA = zacc, accB = zacc;
      float s0 = 0.f, s1 = 0.f;
#pragma unroll
      for (int c = 0; c < 4; ++c) {
        H8 u; u.v = *(const h8*)(hxlds + c * 32 + lg * 8);
        h8 bq = *(const h8*)(plds + p * 264 + c * 32 + lg * 8);
        accA = __builtin_amdgcn_mfma_f32_16x16x32_f16(u.v, bq, accA, 0, 0, 0);
        s0 = fdot2f(u.h[0], u.h[0], s0); s1 = fdot2f(u.h[1], u.h[1], s1);
        s0 = fdot2f(u.h[2], u.h[2], s0); s1 = fdot2f(u.h[3], u.h[3], s1);
      }
#pragma unroll
      for (int c = 4; c < 8; ++c) {
        H8 u; u.v = *(const h8*)(hxlds + c * 32 + lg * 8);
        h8 bq = *(const h8*)(plds + p * 264 + c * 32 + lg * 8);
        accB = __builtin_amdgcn_mfma_f32_16x16x32_f16(u.v, bq, accB, 0, 0, 0);
        s0 = fdot2f(u.h[0], u.h[0], s0); s1 = fdot2f(u.h[1], u.h[1], s1);
        s0 = fdot2f(u.h[2], u.h[2], s0); s1 = fdot2f(u.h[3], u.h[3], s1);
      }
      float hsq = s0 + s1;
      hsq += __shfl_xor(hsq, 16);
      hsq += __shfl_xor(hsq, 32);
      const float d2 = (accA[0] + accB[0]) + hsq + pn + sx_cur;
      const float kk = __expf(-d2);
      if (l < 16) klds[p] = (_Float16)kk;
    }
    bar_lds();  // k ready

    // ---- gates: 4 tiles (one per gate), K=128, bias folded into C-in ----
    f4v acc[4];
#pragma unroll
    for (int g = 0; g < 4; ++g) { acc[g] = zacc; acc[g][0] = bias[g]; }
#pragma unroll
    for (int c = 0; c < 4; ++c) {
      h8 kf = *(const h8*)(klds + c * 32 + lg * 8);
#pragma unroll
      for (int g = 0; g < 4; ++g)
        acc[g] = __builtin_amdgcn_mfma_f32_16x16x32_f16(kf, wfrag[g][c], acc[g], 0, 0, 0);
    }

    // ---- activations + in-register cell update (all lanes valid dups) ----
    const float f_ = sigm_f(acc[0][0]);
    const float i_ = sigm_f(acc[1][0]);
    const float g_ = tanh_f(acc[2][0]);
    const float o_ = sigm_f(acc[3][0]);
    cx = fmaf(f_, cx, i_ * g_);
    hx = o_ * tanh_f(cx);

    if (l < 16) {
      out[((size_t)step * BB + b) * HH + h] = hx;
      hxlds[h] = (_Float16)hx;
    }
    bar_lds();  // hx ready for next step
  }

  if (l < 16) {
    const size_t base = (size_t)TT * BB * HH;
    out[base + (size_t)b * HH + h] = hx;
    out[base + (size_t)BB * HH + (size_t)b * HH + h] = cx;
  }
}

extern "C" void kernel_launch(void* const* d_in, const int* in_sizes, int n_in,
                              void* d_out, int out_size, void* d_ws, size_t ws_size,
                              hipStream_t stream) {
  const float* x     = (const float*)d_in[0];
  const float* proto = (const float*)d_in[1];
  const float* Wf = (const float*)d_in[2];
  const float* bf = (const float*)d_in[3];
  const float* Wi = (const float*)d_in[4];
  const float* bi = (const float*)d_in[5];
  const float* Wg = (const float*)d_in[6];
  const float* bg = (const float*)d_in[7];
  const float* Wo = (const float*)d_in[8];
  const float* bo = (const float*)d_in[9];
  float* out = (float*)d_out;
  _Float16* sxbuf = (_Float16*)d_ws;  // T*B*P*2 = 32 MB

  sx_kernel<<<512, 256, 0, stream>>>(x, proto, sxbuf);
  rec_kernel<<<BB, 1024, 0, stream>>>(sxbuf, proto, Wf, bf, Wi, bi, Wg, bg, Wo, bo, out);
}

// Round 7
// 1036.740 us; speedup vs baseline: 1.2373x; 1.2373x over previous
//
#include <hip/hip_runtime.h>
#include <hip/hip_bf16.h>

// QLSTM: T=512, B=256, D=128, H=256, P=128, GAMMA=1
// Phase 1 (MFMA GEMM): sx[r,p] = ||x_r||^2 + ||px_p||^2 - 2 x_r.px_p  (full Sx, f16, 32MB ws)
// Phase 2: 256 WGs (1 batch row each) x 512 threads (8 waves, 2/SIMD).
//   All dot products on the MFMA pipe (M=1 rows in 16x16x32 f16 tiles).
//   ROUND-7 single-variable fix: amdgpu_waves_per_eu(2,2). Rounds 2-6 all showed
//   the allocator targeting a 64/128-reg bucket for an occupancy the 256-block
//   grid can never use (1 WG/CU), then rematerializing addresses/fragments every
//   step (phantom ~200-900 VALU inst/wave/step, AGPR parking). Capping max
//   waves/EU at 2 grants the full 256-VGPR budget so wfrag(128)+qfrag(32)+
//   acc(~40)+misc stay truly register-resident.

#define TT 512
#define BB 256
#define DD 128
#define HH 256
#define PP 128
#define DHH 384

typedef _Float16 h2 __attribute__((ext_vector_type(2)));
typedef _Float16 h8 __attribute__((ext_vector_type(8)));
typedef float f4v __attribute__((ext_vector_type(4)));

union H8 { h8 v; h2 h[4]; };

__device__ __forceinline__ void pin_h8(h8& v) { asm volatile("" : "+v"(v)); }

// barrier with LDS-only drain: global loads/stores stay in flight.
__device__ __forceinline__ void bar_lds() {
  asm volatile("s_waitcnt lgkmcnt(0)" ::: "memory");
  __builtin_amdgcn_s_barrier();
}

__device__ __forceinline__ float fdot2f(h2 a, h2 b, float c) {
#if __has_builtin(__builtin_amdgcn_fdot2)
  return __builtin_amdgcn_fdot2(a, b, c, false);
#else
  return c + (float)a.x * (float)b.x + (float)a.y * (float)b.y;
#endif
}

__device__ __forceinline__ float sigm_f(float x) { return 1.f / (1.f + __expf(-x)); }
__device__ __forceinline__ float tanh_f(float x) { return 1.f - 2.f / (1.f + __expf(2.f * x)); }

__device__ __forceinline__ h8 pack_h8(float4 a, float4 b2, float s) {
  h8 v;
  v[0] = (_Float16)(s * a.x);  v[1] = (_Float16)(s * a.y);
  v[2] = (_Float16)(s * a.z);  v[3] = (_Float16)(s * a.w);
  v[4] = (_Float16)(s * b2.x); v[5] = (_Float16)(s * b2.y);
  v[6] = (_Float16)(s * b2.z); v[7] = (_Float16)(s * b2.w);
  return v;
}

// ---------------- Phase 1: Sx via MFMA f16 ----------------
__global__ __launch_bounds__(256, 2) void sx_kernel(const float* __restrict__ x,
                                                    const float* __restrict__ proto,
                                                    _Float16* __restrict__ sx) {
  __shared__ __align__(16) _Float16 qlds[PP * 136];   // -2*proto_x, f16
  __shared__ __align__(16) _Float16 xlds[64 * 136];   // x tile, f16
  __shared__ float pnlds[PP];
  __shared__ float xnlds[64];

  const int t = threadIdx.x;
  const int lane = t & 63;
  const int wv = t >> 6;          // wave 0..3 -> m-tile
  const int col = lane & 15;
  const int quad = lane >> 4;
  const int r0 = blockIdx.x * 256;

  // ---- stage q = -2*proto_x (f16) + pnorm ----
  {
    const int p = t >> 1;
    const int hh = t & 1;
    const float* src = proto + p * DHH + hh * 64;
    _Float16* dst = qlds + p * 136 + hh * 64;
    float pn = 0.f;
#pragma unroll
    for (int i = 0; i < 8; ++i) {
      float4 a = *(const float4*)(src + i * 8);
      float4 b = *(const float4*)(src + i * 8 + 4);
      pn = fmaf(a.x, a.x, fmaf(a.y, a.y, fmaf(a.z, a.z, fmaf(a.w, a.w, pn))));
      pn = fmaf(b.x, b.x, fmaf(b.y, b.y, fmaf(b.z, b.z, fmaf(b.w, b.w, pn))));
      *(h8*)(dst + i * 8) = pack_h8(a, b, -2.f);
    }
    pn += __shfl_xor(pn, 1);
    if (hh == 0) pnlds[p] = pn;
  }

  // ---- stage x tile 0 ----
  {
    const int m = t >> 2;
    const int q4 = t & 3;
    const float* xs = x + ((size_t)(r0 + m)) * DD + q4 * 32;
    _Float16* xd = xlds + m * 136 + q4 * 32;
    float xn = 0.f;
#pragma unroll
    for (int i = 0; i < 4; ++i) {
      float4 a = *(const float4*)(xs + i * 8);
      float4 b = *(const float4*)(xs + i * 8 + 4);
      xn = fmaf(a.x, a.x, fmaf(a.y, a.y, fmaf(a.z, a.z, fmaf(a.w, a.w, xn))));
      xn = fmaf(b.x, b.x, fmaf(b.y, b.y, fmaf(b.z, b.z, fmaf(b.w, b.w, xn))));
      *(h8*)(xd + i * 8) = pack_h8(a, b, 1.f);
    }
    xn += __shfl_xor(xn, 1);
    xn += __shfl_xor(xn, 2);
    if (q4 == 0) xnlds[m] = xn;
  }
  __syncthreads();

  float pn8[8];
#pragma unroll
  for (int nt = 0; nt < 8; ++nt) pn8[nt] = pnlds[nt * 16 + col];

  for (int tile = 0; tile < 4; ++tile) {
    h8 af[4];
#pragma unroll
    for (int kc = 0; kc < 4; ++kc)
      af[kc] = *(const h8*)(xlds + (wv * 16 + col) * 136 + kc * 32 + quad * 8);
    float xnq[4];
#pragma unroll
    for (int r = 0; r < 4; ++r) xnq[r] = xnlds[wv * 16 + quad * 4 + r];

#pragma unroll
    for (int nt = 0; nt < 8; ++nt) {
      f4v acc;
      acc[0] = pn8[nt]; acc[1] = pn8[nt]; acc[2] = pn8[nt]; acc[3] = pn8[nt];
#pragma unroll
      for (int kc = 0; kc < 4; ++kc) {
        h8 bf = *(const h8*)(qlds + (nt * 16 + col) * 136 + kc * 32 + quad * 8);
        acc = __builtin_amdgcn_mfma_f32_16x16x32_f16(af[kc], bf, acc, 0, 0, 0);
      }
#pragma unroll
      for (int r = 0; r < 4; ++r) {
        const int row = r0 + tile * 64 + wv * 16 + quad * 4 + r;
        sx[(size_t)row * PP + nt * 16 + col] = (_Float16)(acc[r] + xnq[r]);
      }
    }

    if (tile < 3) {
      __syncthreads();
      const int m = t >> 2;
      const int q4 = t & 3;
      const float* xs = x + ((size_t)(r0 + (tile + 1) * 64 + m)) * DD + q4 * 32;
      _Float16* xd = xlds + m * 136 + q4 * 32;
      float xn = 0.f;
#pragma unroll
      for (int i = 0; i < 4; ++i) {
        float4 a = *(const float4*)(xs + i * 8);
        float4 b = *(const float4*)(xs + i * 8 + 4);
        xn = fmaf(a.x, a.x, fmaf(a.y, a.y, fmaf(a.z, a.z, fmaf(a.w, a.w, xn))));
        xn = fmaf(b.x, b.x, fmaf(b.y, b.y, fmaf(b.z, b.z, fmaf(b.w, b.w, xn))));
        *(h8*)(xd + i * 8) = pack_h8(a, b, 1.f);
      }
      xn += __shfl_xor(xn, 1);
      xn += __shfl_xor(xn, 2);
      if (q4 == 0) xnlds[m] = xn;
      __syncthreads();
    }
  }
}

// ---------------- Phase 2: sequential recurrence (MFMA GEMV) ----------------
__global__ __launch_bounds__(512)
__attribute__((amdgpu_waves_per_eu(2, 2)))
void rec_kernel(
    const _Float16* __restrict__ sx, const float* __restrict__ proto,
    const float* __restrict__ Wf, const float* __restrict__ bfv,
    const float* __restrict__ Wi, const float* __restrict__ biv,
    const float* __restrict__ Wg, const float* __restrict__ bgv,
    const float* __restrict__ Wo, const float* __restrict__ bov,
    float* __restrict__ out) {
  const int b = blockIdx.x;
  const int t = threadIdx.x;
  const int w = t >> 6;     // wave 0..7
  const int l = t & 63;
  const int lc = l & 15;    // B-frag column / C column
  const int lg = l >> 4;    // k-group 0..3 (8 contiguous k elems each)

  const float* const Warr[4] = {Wf, Wi, Wg, Wo};
  const float* const barr[4] = {bfv, biv, bgv, bov};

  // ---- gate B-frags: tile (g, st): B[k=p][col=h], h = w*32 + st*16 + lc ----
  h8 wfrag[4][2][4];
  float bias[4][2];
#pragma unroll
  for (int g = 0; g < 4; ++g) {
#pragma unroll
    for (int st = 0; st < 2; ++st) {
      const int h = w * 32 + st * 16 + lc;
      const float* row = Warr[g] + (size_t)h * PP;
      bias[g][st] = barr[g][h];
#pragma unroll
      for (int c = 0; c < 4; ++c) {
        float4 a = *(const float4*)(row + c * 32 + lg * 8);
        float4 b2 = *(const float4*)(row + c * 32 + lg * 8 + 4);
        wfrag[g][st][c] = pack_h8(a, b2, 1.f);
      }
    }
  }
#pragma unroll
  for (int g = 0; g < 4; ++g)
#pragma unroll
    for (int st = 0; st < 2; ++st)
#pragma unroll
      for (int c = 0; c < 4; ++c) pin_h8(wfrag[g][st][c]);

  // ---- Sh B-frags (-2 * proto_h^T): tile w covers p = w*16 + lc ----
  const int p = w * 16 + lc;
  h8 qfrag[8];
  float pn = 0.f;
#pragma unroll
  for (int c = 0; c < 8; ++c) {
    const float* src = proto + (size_t)p * DHH + DD + c * 32 + lg * 8;
    float4 a = *(const float4*)(src);
    float4 b2 = *(const float4*)(src + 4);
    pn = fmaf(a.x, a.x, fmaf(a.y, a.y, fmaf(a.z, a.z, fmaf(a.w, a.w, pn))));
    pn = fmaf(b2.x, b2.x, fmaf(b2.y, b2.y, fmaf(b2.z, b2.z, fmaf(b2.w, b2.w, pn))));
    qfrag[c] = pack_h8(a, b2, -2.f);
  }
#pragma unroll
  for (int c = 0; c < 8; ++c) pin_h8(qfrag[c]);
  pn += __shfl_xor(pn, 16);   // sum over the 4 lg groups (same p)
  pn += __shfl_xor(pn, 32);

  __shared__ __align__(16) _Float16 hxlds[HH];  // hx, f16
  __shared__ __align__(16) _Float16 klds[PP];   // k, f16

  if (t < HH) hxlds[t] = (_Float16)0.f;
  float cx0 = 0.f, cx1 = 0.f, hx0 = 0.f, hx1 = 0.f;
  __syncthreads();

  float sx_next = (float)sx[(size_t)b * PP + p];

  const f4v zacc = {0.f, 0.f, 0.f, 0.f};

  for (int step = 0; step < TT; ++step) {
    // ---- prefetch next sx early (stays in flight across raw barriers) ----
    const float sx_cur = sx_next;
    const int nst = (step + 1 < TT) ? (step + 1) : (TT - 1);
    sx_next = (float)sx[((size_t)nst * BB + b) * PP + p];

    // ---- Sh MFMA + fused |hx|^2 (fdot2 on the same fragments) ----
    f4v accA = zacc, accB = zacc;
    float s0 = 0.f, s1 = 0.f;
#pragma unroll
    for (int c = 0; c < 4; ++c) {
      H8 u; u.v = *(const h8*)(hxlds + c * 32 + lg * 8);
      accA = __builtin_amdgcn_mfma_f32_16x16x32_f16(u.v, qfrag[c], accA, 0, 0, 0);
      s0 = fdot2f(u.h[0], u.h[0], s0); s1 = fdot2f(u.h[1], u.h[1], s1);
      s0 = fdot2f(u.h[2], u.h[2], s0); s1 = fdot2f(u.h[3], u.h[3], s1);
    }
#pragma unroll
    for (int c = 4; c < 8; ++c) {
      H8 u; u.v = *(const h8*)(hxlds + c * 32 + lg * 8);
      accB = __builtin_amdgcn_mfma_f32_16x16x32_f16(u.v, qfrag[c], accB, 0, 0, 0);
      s0 = fdot2f(u.h[0], u.h[0], s0); s1 = fdot2f(u.h[1], u.h[1], s1);
      s0 = fdot2f(u.h[2], u.h[2], s0); s1 = fdot2f(u.h[3], u.h[3], s1);
    }
    float hsq = s0 + s1;              // this lane's 64 dims
    hsq += __shfl_xor(hsq, 16);       // fold the 4 lg groups
    hsq += __shfl_xor(hsq, 32);

    const float d2 = (accA[0] + accB[0]) + hsq + pn + sx_cur;
    const float kk = __expf(-d2);
    if (l < 16) klds[p] = (_Float16)kk;
    bar_lds();  // k ready (LDS-only drain; global ops keep flying)

    // ---- gates: 4 gates x 2 subtiles, K=128 (4 chained MFMA each) ----
    f4v acc[4][2];
#pragma unroll
    for (int g = 0; g < 4; ++g)
#pragma unroll
      for (int st = 0; st < 2; ++st) acc[g][st] = zacc;
#pragma unroll
    for (int c = 0; c < 4; ++c) {
      h8 kf = *(const h8*)(klds + c * 32 + lg * 8);
#pragma unroll
      for (int g = 0; g < 4; ++g) {
#pragma unroll
        for (int st = 0; st < 2; ++st)
          acc[g][st] = __builtin_amdgcn_mfma_f32_16x16x32_f16(kf, wfrag[g][st][c],
                                                              acc[g][st], 0, 0, 0);
      }
    }

    // ---- activations + in-register cell update (all lanes hold valid dups) ----
    const float f0 = sigm_f(acc[0][0][0] + bias[0][0]);
    const float i0 = sigm_f(acc[1][0][0] + bias[1][0]);
    const float g0 = tanh_f(acc[2][0][0] + bias[2][0]);
    const float o0 = sigm_f(acc[3][0][0] + bias[3][0]);
    const float f1 = sigm_f(acc[0][1][0] + bias[0][1]);
    const float i1 = sigm_f(acc[1][1][0] + bias[1][1]);
    const float g1 = tanh_f(acc[2][1][0] + bias[2][1]);
    const float o1 = sigm_f(acc[3][1][0] + bias[3][1]);

    cx0 = fmaf(f0, cx0, i0 * g0);
    cx1 = fmaf(f1, cx1, i1 * g1);
    hx0 = o0 * tanh_f(cx0);
    hx1 = o1 * tanh_f(cx1);

    const int h0 = w * 32 + lc;
    if (l < 16) {
      out[((size_t)step * BB + b) * HH + h0] = hx0;
      out[((size_t)step * BB + b) * HH + h0 + 16] = hx1;
      hxlds[h0] = (_Float16)hx0;
      hxlds[h0 + 16] = (_Float16)hx1;
    }
    bar_lds();  // hx ready for next step (LDS-only drain)
  }

  if (l < 16) {
    const int h0 = w * 32 + lc;
    const size_t base = (size_t)TT * BB * HH;
    out[base + (size_t)b * HH + h0] = hx0;
    out[base + (size_t)b * HH + h0 + 16] = hx1;
    out[base + (size_t)BB * HH + (size_t)b * HH + h0] = cx0;
    out[base + (size_t)BB * HH + (size_t)b * HH + h0 + 16] = cx1;
  }
}

extern "C" void kernel_launch(void* const* d_in, const int* in_sizes, int n_in,
                              void* d_out, int out_size, void* d_ws, size_t ws_size,
                              hipStream_t stream) {
  const float* x     = (const float*)d_in[0];
  const float* proto = (const float*)d_in[1];
  const float* Wf = (const float*)d_in[2];
  const float* bf = (const float*)d_in[3];
  const float* Wi = (const float*)d_in[4];
  const float* bi = (const float*)d_in[5];
  const float* Wg = (const float*)d_in[6];
  const float* bg = (const float*)d_in[7];
  const float* Wo = (const float*)d_in[8];
  const float* bo = (const float*)d_in[9];
  float* out = (float*)d_out;
  _Float16* sxbuf = (_Float16*)d_ws;  // T*B*P*2 = 32 MB

  sx_kernel<<<512, 256, 0, stream>>>(x, proto, sxbuf);
  rec_kernel<<<BB, 512, 0, stream>>>(sxbuf, proto, Wf, bf, Wi, bi, Wg, bg, Wo, bo, out);
}